// Round 2
// baseline (222.065 us; speedup 1.0000x reference)
//
#include <hip/hip_runtime.h>
#include <math.h>

#define B_ 32
#define C_ 3
#define H_ 512
#define W_ 512
#define NOUT 64
#define FAN (C_*H_*W_)          // 786432

// locnet decomposition
#define CHUNKS 192
#define CELEMS (FAN / CHUNKS)   // 4096
#define BGROUPS 4               // 8 batches per block

// workspace layout:
//   floats [0, 192*160): per-chunk locnet partials P[chunk][b][j] (overwritten each call)
//   floats [GAMMA_OFF, +32): gamma[b] (written by k_filters)
//   then ushort images (base = ws + PFLOATS floats):
//     FxH [32][64][512], FxL, FyH, FyL  (1,048,576 ushorts = 2MB each)
#define PPART_STRIDE 160
#define GAMMA_OFF (CHUNKS * PPART_STRIDE)   // 30720
#define PFLOATS 32768
#define FXH_U 0
#define FXL_U 1048576
#define FYH_U 2097152
#define FYL_U 3145728

typedef __bf16 bf16x8 __attribute__((ext_vector_type(8)));
typedef float f32x4 __attribute__((ext_vector_type(4)));

// round-to-nearest-even fp32 -> bf16 (as ushort) — integer emulation (exact RNE)
__device__ __forceinline__ unsigned short f2bf(float f) {
    unsigned int u = __float_as_uint(f);
    u = (u + 0x7FFFu + ((u >> 16) & 1u)) >> 16;
    return (unsigned short)u;
}
__device__ __forceinline__ float bf2f(unsigned short h) {
    return __uint_as_float(((unsigned int)h) << 16);
}
// packed fp32x2 -> bf16x2 in one VALU op (hw RNE; identical results to f2bf)
__device__ __forceinline__ unsigned int cvt_pk_bf16(float lo, float hi) {
    unsigned int r;
    asm("v_cvt_pk_bf16_f32 %0, %1, %2" : "=v"(r) : "v"(lo), "v"(hi));
    return r;
}

// ---------------- kernel 1: partial p[b,j] = sum_i X[b,i] * W_loc[i,j] ----------------
// Non-atomic: block (chunk, bgroup) writes its 40 partials to ws[chunk*160 + b0*5 + ..]
__global__ __launch_bounds__(256) void k_locnet(const float* __restrict__ X,
                                                const float* __restrict__ Wl,
                                                float* __restrict__ ws) {
    const int chunk = blockIdx.x;      // 0..CHUNKS-1
    const int b0 = blockIdx.y * 8;     // 0,8,16,24
    const int t = threadIdx.x;

    float acc[8][5] = {};
    const size_t base = (size_t)chunk * CELEMS;

    for (int k = t; k < CELEMS / 4; k += 256) {   // 4 iterations
        const size_t i0 = base + (size_t)k * 4;
        const float4* W4 = (const float4*)(Wl + i0 * 5);
        float4 w0 = W4[0], w1 = W4[1], w2 = W4[2], w3 = W4[3], w4 = W4[4];
        float wv[20] = {w0.x, w0.y, w0.z, w0.w,
                        w1.x, w1.y, w1.z, w1.w,
                        w2.x, w2.y, w2.z, w2.w,
                        w3.x, w3.y, w3.z, w3.w,
                        w4.x, w4.y, w4.z, w4.w};
        #pragma unroll
        for (int bb = 0; bb < 8; bb++) {
            float4 x = *(const float4*)(X + (size_t)(b0 + bb) * FAN + i0);
            float xv[4] = {x.x, x.y, x.z, x.w};
            #pragma unroll
            for (int e = 0; e < 4; e++)
                #pragma unroll
                for (int j = 0; j < 5; j++)
                    acc[bb][j] += xv[e] * wv[e * 5 + j];
        }
    }

    #pragma unroll
    for (int off = 32; off > 0; off >>= 1)
        #pragma unroll
        for (int bb = 0; bb < 8; bb++)
            #pragma unroll
            for (int j = 0; j < 5; j++)
                acc[bb][j] += __shfl_down(acc[bb][j], off);

    __shared__ float sred[4][40];
    const int wave = t >> 6, lane = t & 63;
    if (lane == 0) {
        #pragma unroll
        for (int bb = 0; bb < 8; bb++)
            #pragma unroll
            for (int j = 0; j < 5; j++)
                sred[wave][bb * 5 + j] = acc[bb][j];
    }
    __syncthreads();
    if (t < 40) {
        float s = sred[0][t] + sred[1][t] + sred[2][t] + sred[3][t];
        ws[(size_t)chunk * PPART_STRIDE + b0 * 5 + t] = s;
    }
}

// ---------------- kernel 2: reduce p, build normalized filters (bf16 hi/lo), zero out ----------------
__global__ __launch_bounds__(256) void k_filters(const float* __restrict__ bl,
                                                 float* __restrict__ ws,
                                                 float* __restrict__ out) {
    const int n = blockIdx.x;
    const int b = blockIdx.y;
    const int which = blockIdx.z;
    const int t = threadIdx.x;

    // zero a 96-float slice of out (replaces a 1.5MB memset dispatch)
    {
        const int bid = blockIdx.x + NOUT * (blockIdx.y + B_ * blockIdx.z);  // 0..4095
        if (t < 24) {
            ((float4*)out)[(size_t)bid * 24 + t] = make_float4(0.f, 0.f, 0.f, 0.f);
        }
    }

    // reduce locnet partials: p[j] = bl[j] + sum_{chunk<192} ws[chunk*160 + b*5 + j]
    float pj[5] = {0.f, 0.f, 0.f, 0.f, 0.f};
    if (t < CHUNKS) {
        const float* pr = ws + (size_t)t * PPART_STRIDE + b * 5;
        #pragma unroll
        for (int j = 0; j < 5; j++) pj[j] = pr[j];
    }
    #pragma unroll
    for (int off = 32; off > 0; off >>= 1)
        #pragma unroll
        for (int j = 0; j < 5; j++) pj[j] += __shfl_down(pj[j], off);

    __shared__ float spart[4][5];
    __shared__ float pfin[5];
    const int wave = t >> 6, lane = t & 63;
    if (lane == 0) {
        #pragma unroll
        for (int j = 0; j < 5; j++) spart[wave][j] = pj[j];
    }
    __syncthreads();
    if (t < 5) pfin[t] = spart[0][t] + spart[1][t] + spart[2][t] + spart[3][t] + bl[t];
    __syncthreads();

    const float p0 = pfin[0], p1 = pfin[1], p2 = pfin[2], p3 = pfin[3];
    if (which == 0 && n == 0 && t == 0) ws[GAMMA_OFF + b] = expf(pfin[4]);

    const float g = (which == 0) ? 32.f * (p0 + 1.f) : 32.f * (p1 + 1.f);
    const float sigma2 = expf(p2);
    const float inv2s = 0.5f / sigma2;
    const float delta = expf(p3) * (511.0f / 63.0f);
    const float mean = g + delta * ((float)n - 32.5f);

    // thread t handles elements 2t, 2t+1 (enables packed 4B stores)
    float d0 = (float)(2 * t) - mean;
    float f0 = expf(-d0 * d0 * inv2s);
    float d1 = (float)(2 * t + 1) - mean;
    float f1 = expf(-d1 * d1 * inv2s);

    float s = f0 + f1;
    #pragma unroll
    for (int off = 32; off > 0; off >>= 1) s += __shfl_down(s, off);
    __shared__ float sred[4];
    __shared__ float stot;
    if (lane == 0) sred[wave] = s;
    __syncthreads();
    if (t == 0) stot = sred[0] + sred[1] + sred[2] + sred[3] + 1e-4f;
    __syncthreads();
    const float scale = 1.0f / stot;

    unsigned short* wsu = (unsigned short*)(ws + PFLOATS);
    unsigned int* dstH = (unsigned int*)(wsu + (which ? FYH_U : FXH_U) + ((size_t)b * NOUT + n) * 512);
    unsigned int* dstL = (unsigned int*)(wsu + (which ? FYL_U : FXL_U) + ((size_t)b * NOUT + n) * 512);

    float v0 = f0 * scale;
    float v1 = f1 * scale;
    unsigned short h0 = f2bf(v0);
    unsigned short h1 = f2bf(v1);
    unsigned short l0 = f2bf(v0 - bf2f(h0));
    unsigned short l1 = f2bf(v1 - bf2f(h1));
    dstH[t] = (unsigned int)h0 | ((unsigned int)h1 << 16);
    dstL[t] = (unsigned int)l0 | ((unsigned int)l1 << 16);
}

// ---------------- kernel 3: MFMA glimpse (software-pipelined staging) ----------------
// out[b,c] += gamma * Fy_chunk @ (X_chunk @ Fx^T), split-bf16 (hi+lo) MFMA.
// grid (8 hc, 96 bc), 256 threads = 4 waves.
// Per w-tile: LDS-write staged regs -> barrier -> prefetch next tile into regs
// (latency hides under MFMA) -> MFMA -> barrier.
#define KC 64
#define PITCH 72            // ushorts per LDS row (16B-aligned rows, low-conflict)
#define TSZ (64 * PITCH)    // 4608 ushorts per array

#define LOAD_X(wt_) do {                                                      \
    const int wbase_ = (wt_) * KC;                                            \
    _Pragma("unroll")                                                         \
    for (int k4 = 0; k4 < 4; k4++) {                                          \
        int idx_ = t + 256 * k4;                                              \
        int row_ = idx_ >> 4;                                                 \
        int c4_ = (idx_ & 15) * 4;                                            \
        xr[k4] = *(const float4*)(Xp + (size_t)row_ * W_ + wbase_ + c4_);     \
    } } while (0)

#define LOAD_F(Hp_, Lp_, coff_) do {                                          \
    _Pragma("unroll")                                                         \
    for (int i_ = 0; i_ < 2; i_++) {                                          \
        int idx_ = t + 256 * i_;                                              \
        int row_ = idx_ >> 3;                                                 \
        int c8_ = (idx_ & 7) * 8;                                             \
        fhr[i_] = *(const uint4*)((Hp_) + (size_t)row_ * 512 + (coff_) + c8_);\
        flr[i_] = *(const uint4*)((Lp_) + (size_t)row_ * 512 + (coff_) + c8_);\
    } } while (0)

__global__ __launch_bounds__(256) void k_glimpse(const float* __restrict__ X,
                                                 const float* __restrict__ ws,
                                                 float* __restrict__ out) {
    const int hc = blockIdx.x;   // 0..7
    const int bc = blockIdx.y;   // 0..95
    const int b = bc / 3;
    const int t = threadIdx.x;
    const int lane = t & 63;
    const int wv = t >> 6;       // 0..3
    const int l15 = lane & 15;
    const int quad = lane >> 4;  // 0..3
    const int hbase = hc * 64;

    __shared__ __align__(16) unsigned short lds[4 * TSZ];   // 36864 B
    unsigned short* Xh = lds;             // X hi   -> later Gt hi
    unsigned short* Xl = lds + TSZ;       // X lo   -> later Gt lo
    unsigned short* Fh = lds + 2 * TSZ;   // Fx hi  -> later Fy hi
    unsigned short* Fl = lds + 3 * TSZ;   // Fx lo  -> later Fy lo

    const float* Xp = X + (size_t)bc * (H_ * W_) + (size_t)hbase * W_;
    const unsigned short* wsu = (const unsigned short*)(ws + PFLOATS);
    const unsigned short* FxHp = wsu + FXH_U + (size_t)b * NOUT * 512;
    const unsigned short* FxLp = wsu + FXL_U + (size_t)b * NOUT * 512;
    const unsigned short* FyHp = wsu + FYH_U + (size_t)b * NOUT * 512;
    const unsigned short* FyLp = wsu + FYL_U + (size_t)b * NOUT * 512;

    float4 xr[4];
    uint4 fhr[2], flr[2];
    LOAD_X(0);
    LOAD_F(FxHp, FxLp, 0);

    f32x4 acc[4] = {};   // G: wave rows [16wv,+16), 4 m-tiles

    for (int wt = 0; wt < 8; wt++) {
        // ---- LDS write of prefetched regs ----
        #pragma unroll
        for (int k4 = 0; k4 < 4; k4++) {
            int idx = t + 256 * k4;
            int row = idx >> 4;            // 0..63
            int c4 = (idx & 15) * 4;       // 0,4,..60
            float4 v = xr[k4];
            unsigned int h01 = cvt_pk_bf16(v.x, v.y);
            unsigned int h23 = cvt_pk_bf16(v.z, v.w);
            float r0 = __uint_as_float(h01 << 16);
            float r1 = __uint_as_float(h01 & 0xffff0000u);
            float r2 = __uint_as_float(h23 << 16);
            float r3 = __uint_as_float(h23 & 0xffff0000u);
            unsigned int l01 = cvt_pk_bf16(v.x - r0, v.y - r1);
            unsigned int l23 = cvt_pk_bf16(v.z - r2, v.w - r3);
            int o = row * PITCH + c4;
            *(uint2*)&Xh[o] = make_uint2(h01, h23);
            *(uint2*)&Xl[o] = make_uint2(l01, l23);
        }
        #pragma unroll
        for (int i = 0; i < 2; i++) {
            int idx = t + 256 * i;
            int row = idx >> 3;
            int c8 = (idx & 7) * 8;
            *(uint4*)&Fh[row * PITCH + c8] = fhr[i];
            *(uint4*)&Fl[row * PITCH + c8] = flr[i];
        }
        __syncthreads();

        // ---- prefetch next tile (latency hides under MFMA below) ----
        if (wt < 7) {
            LOAD_X(wt + 1);
            LOAD_F(FxHp, FxLp, (wt + 1) * KC);
        } else {
            LOAD_F(FyHp, FyLp, hbase);     // prefetch Fy for GEMM2 staging
        }

        // ---- MFMA on current tile ----
        #pragma unroll
        for (int ks = 0; ks < 2; ks++) {
            const int ko = ks * 32 + quad * 8;
            bf16x8 ah = *(const bf16x8*)&Xh[(16 * wv + l15) * PITCH + ko];
            bf16x8 al = *(const bf16x8*)&Xl[(16 * wv + l15) * PITCH + ko];
            #pragma unroll
            for (int mt = 0; mt < 4; mt++) {
                bf16x8 bh = *(const bf16x8*)&Fh[(16 * mt + l15) * PITCH + ko];
                bf16x8 bl2 = *(const bf16x8*)&Fl[(16 * mt + l15) * PITCH + ko];
                acc[mt] = __builtin_amdgcn_mfma_f32_16x16x32_bf16(ah, bh, acc[mt], 0, 0, 0);
                acc[mt] = __builtin_amdgcn_mfma_f32_16x16x32_bf16(al, bh, acc[mt], 0, 0, 0);
                acc[mt] = __builtin_amdgcn_mfma_f32_16x16x32_bf16(ah, bl2, acc[mt], 0, 0, 0);
            }
        }
        __syncthreads();
    }

    // write G transposed as hi/lo into Xh/Xl region: Gt[m][h]
    #pragma unroll
    for (int mt = 0; mt < 4; mt++) {
        float g0 = acc[mt][0], g1 = acc[mt][1], g2 = acc[mt][2], g3 = acc[mt][3];
        unsigned int h01 = cvt_pk_bf16(g0, g1);
        unsigned int h23 = cvt_pk_bf16(g2, g3);
        float r0 = __uint_as_float(h01 << 16);
        float r1 = __uint_as_float(h01 & 0xffff0000u);
        float r2 = __uint_as_float(h23 << 16);
        float r3 = __uint_as_float(h23 & 0xffff0000u);
        unsigned int l01 = cvt_pk_bf16(g0 - r0, g1 - r1);
        unsigned int l23 = cvt_pk_bf16(g2 - r2, g3 - r3);
        int m = 16 * mt + l15;
        int h = 16 * wv + quad * 4;      // rows quad*4+r, r contiguous
        int o = m * PITCH + h;
        *(uint2*)&Xh[o] = make_uint2(h01, h23);
        *(uint2*)&Xl[o] = make_uint2(l01, l23);
    }

    // stage Fy chunk hi/lo into Fh/Fl from prefetched regs
    #pragma unroll
    for (int i = 0; i < 2; i++) {
        int idx = t + 256 * i;
        int row = idx >> 3;               // n: 0..63
        int c8 = (idx & 7) * 8;           // local h: 0,8,..56
        *(uint4*)&Fh[row * PITCH + c8] = fhr[i];
        *(uint4*)&Fl[row * PITCH + c8] = flr[i];
    }
    __syncthreads();

    // GEMM2: P[n][m] = sum_h Fy[n][h] * G[h][m]
    f32x4 p[4] = {};
    #pragma unroll
    for (int ks = 0; ks < 2; ks++) {
        const int ko = ks * 32 + quad * 8;
        bf16x8 yh = *(const bf16x8*)&Fh[(16 * wv + l15) * PITCH + ko];
        bf16x8 yl = *(const bf16x8*)&Fl[(16 * wv + l15) * PITCH + ko];
        #pragma unroll
        for (int mt = 0; mt < 4; mt++) {
            bf16x8 gh = *(const bf16x8*)&Xh[(16 * mt + l15) * PITCH + ko];
            bf16x8 gl = *(const bf16x8*)&Xl[(16 * mt + l15) * PITCH + ko];
            p[mt] = __builtin_amdgcn_mfma_f32_16x16x32_bf16(yh, gh, p[mt], 0, 0, 0);
            p[mt] = __builtin_amdgcn_mfma_f32_16x16x32_bf16(yl, gh, p[mt], 0, 0, 0);
            p[mt] = __builtin_amdgcn_mfma_f32_16x16x32_bf16(yh, gl, p[mt], 0, 0, 0);
        }
    }

    const float gamma = ws[GAMMA_OFF + b];
    float* outp = out + (size_t)bc * (NOUT * NOUT);
    #pragma unroll
    for (int mt = 0; mt < 4; mt++)
        #pragma unroll
        for (int r = 0; r < 4; r++) {
            int n = 16 * wv + quad * 4 + r;
            int m = 16 * mt + l15;
            atomicAdd(&outp[n * NOUT + m], gamma * p[mt][r]);
        }
}

extern "C" void kernel_launch(void* const* d_in, const int* in_sizes, int n_in,
                              void* d_out, int out_size, void* d_ws, size_t ws_size,
                              hipStream_t stream) {
    const float* X  = (const float*)d_in[0];
    const float* Wl = (const float*)d_in[1];
    const float* bl = (const float*)d_in[2];
    float* out = (float*)d_out;
    float* ws  = (float*)d_ws;

    k_locnet<<<dim3(CHUNKS, BGROUPS), 256, 0, stream>>>(X, Wl, ws);
    k_filters<<<dim3(NOUT, B_, 2), 256, 0, stream>>>(bl, ws, out);
    k_glimpse<<<dim3(8, B_ * C_), 256, 0, stream>>>(X, ws, out);
}

// Round 3
// 203.908 us; speedup vs baseline: 1.0890x; 1.0890x over previous
//
#include <hip/hip_runtime.h>
#include <math.h>

#define B_ 32
#define C_ 3
#define H_ 512
#define W_ 512
#define NOUT 64
#define FAN (C_*H_*W_)          // 786432

// locnet decomposition
#define CHUNKS 192
#define CELEMS (FAN / CHUNKS)   // 4096
#define BGROUPS 4               // 8 batches per block

// workspace layout:
//   floats [0, 192*160): per-chunk locnet partials P[chunk][b][j]
//   floats [GAMMA_OFF, +32): gamma[b] (written by k_filters)
//   then ushort images (base = ws + PFLOATS floats):
//     FxH [32][64][512], FxL, FyH, FyL  (1,048,576 ushorts = 2MB each)
#define PPART_STRIDE 160
#define GAMMA_OFF (CHUNKS * PPART_STRIDE)   // 30720
#define PFLOATS 32768
#define FXH_U 0
#define FXL_U 1048576
#define FYH_U 2097152
#define FYL_U 3145728

typedef __bf16 bf16x8 __attribute__((ext_vector_type(8)));
typedef float f32x4 __attribute__((ext_vector_type(4)));

// round-to-nearest-even fp32 -> bf16 (as ushort) — integer emulation (exact RNE)
__device__ __forceinline__ unsigned short f2bf(float f) {
    unsigned int u = __float_as_uint(f);
    u = (u + 0x7FFFu + ((u >> 16) & 1u)) >> 16;
    return (unsigned short)u;
}
__device__ __forceinline__ float bf2f(unsigned short h) {
    return __uint_as_float(((unsigned int)h) << 16);
}
// packed fp32x2 -> bf16x2 in one VALU op (hw RNE; identical results to f2bf)
__device__ __forceinline__ unsigned int cvt_pk_bf16(float lo, float hi) {
    unsigned int r;
    asm("v_cvt_pk_bf16_f32 %0, %1, %2" : "=v"(r) : "v"(lo), "v"(hi));
    return r;
}

union BF8U { uint4 u; bf16x8 v; };

// ---------------- kernel 1: partial p[b,j] = sum_i X[b,i] * W_loc[i,j] ----------------
__global__ __launch_bounds__(256) void k_locnet(const float* __restrict__ X,
                                                const float* __restrict__ Wl,
                                                float* __restrict__ ws) {
    const int chunk = blockIdx.x;      // 0..CHUNKS-1
    const int b0 = blockIdx.y * 8;     // 0,8,16,24
    const int t = threadIdx.x;

    float acc[8][5] = {};
    const size_t base = (size_t)chunk * CELEMS;

    for (int k = t; k < CELEMS / 4; k += 256) {   // 4 iterations
        const size_t i0 = base + (size_t)k * 4;
        const float4* W4 = (const float4*)(Wl + i0 * 5);
        float4 w0 = W4[0], w1 = W4[1], w2 = W4[2], w3 = W4[3], w4 = W4[4];
        float wv[20] = {w0.x, w0.y, w0.z, w0.w,
                        w1.x, w1.y, w1.z, w1.w,
                        w2.x, w2.y, w2.z, w2.w,
                        w3.x, w3.y, w3.z, w3.w,
                        w4.x, w4.y, w4.z, w4.w};
        #pragma unroll
        for (int bb = 0; bb < 8; bb++) {
            float4 x = *(const float4*)(X + (size_t)(b0 + bb) * FAN + i0);
            float xv[4] = {x.x, x.y, x.z, x.w};
            #pragma unroll
            for (int e = 0; e < 4; e++)
                #pragma unroll
                for (int j = 0; j < 5; j++)
                    acc[bb][j] += xv[e] * wv[e * 5 + j];
        }
    }

    #pragma unroll
    for (int off = 32; off > 0; off >>= 1)
        #pragma unroll
        for (int bb = 0; bb < 8; bb++)
            #pragma unroll
            for (int j = 0; j < 5; j++)
                acc[bb][j] += __shfl_down(acc[bb][j], off);

    __shared__ float sred[4][40];
    const int wave = t >> 6, lane = t & 63;
    if (lane == 0) {
        #pragma unroll
        for (int bb = 0; bb < 8; bb++)
            #pragma unroll
            for (int j = 0; j < 5; j++)
                sred[wave][bb * 5 + j] = acc[bb][j];
    }
    __syncthreads();
    if (t < 40) {
        float s = sred[0][t] + sred[1][t] + sred[2][t] + sred[3][t];
        ws[(size_t)chunk * PPART_STRIDE + b0 * 5 + t] = s;
    }
}

// ---------------- kernel 2: reduce p, build normalized filters (bf16 hi/lo), zero out ----------------
__global__ __launch_bounds__(256) void k_filters(const float* __restrict__ bl,
                                                 float* __restrict__ ws,
                                                 float* __restrict__ out) {
    const int n = blockIdx.x;
    const int b = blockIdx.y;
    const int which = blockIdx.z;
    const int t = threadIdx.x;

    // zero a 96-float slice of out (replaces a 1.5MB memset dispatch)
    {
        const int bid = blockIdx.x + NOUT * (blockIdx.y + B_ * blockIdx.z);  // 0..4095
        if (t < 24) {
            ((float4*)out)[(size_t)bid * 24 + t] = make_float4(0.f, 0.f, 0.f, 0.f);
        }
    }

    // reduce locnet partials: p[j] = bl[j] + sum_{chunk<192} ws[chunk*160 + b*5 + j]
    float pj[5] = {0.f, 0.f, 0.f, 0.f, 0.f};
    if (t < CHUNKS) {
        const float* pr = ws + (size_t)t * PPART_STRIDE + b * 5;
        #pragma unroll
        for (int j = 0; j < 5; j++) pj[j] = pr[j];
    }
    #pragma unroll
    for (int off = 32; off > 0; off >>= 1)
        #pragma unroll
        for (int j = 0; j < 5; j++) pj[j] += __shfl_down(pj[j], off);

    __shared__ float spart[4][5];
    __shared__ float pfin[5];
    const int wave = t >> 6, lane = t & 63;
    if (lane == 0) {
        #pragma unroll
        for (int j = 0; j < 5; j++) spart[wave][j] = pj[j];
    }
    __syncthreads();
    if (t < 5) pfin[t] = spart[0][t] + spart[1][t] + spart[2][t] + spart[3][t] + bl[t];
    __syncthreads();

    const float p0 = pfin[0], p1 = pfin[1], p2 = pfin[2], p3 = pfin[3];
    if (which == 0 && n == 0 && t == 0) ws[GAMMA_OFF + b] = expf(pfin[4]);

    const float g = (which == 0) ? 32.f * (p0 + 1.f) : 32.f * (p1 + 1.f);
    const float sigma2 = expf(p2);
    const float inv2s = 0.5f / sigma2;
    const float delta = expf(p3) * (511.0f / 63.0f);
    const float mean = g + delta * ((float)n - 32.5f);

    // thread t handles elements 2t, 2t+1 (packed 4B stores)
    float d0 = (float)(2 * t) - mean;
    float f0 = expf(-d0 * d0 * inv2s);
    float d1 = (float)(2 * t + 1) - mean;
    float f1 = expf(-d1 * d1 * inv2s);

    float s = f0 + f1;
    #pragma unroll
    for (int off = 32; off > 0; off >>= 1) s += __shfl_down(s, off);
    __shared__ float sred[4];
    __shared__ float stot;
    if (lane == 0) sred[wave] = s;
    __syncthreads();
    if (t == 0) stot = sred[0] + sred[1] + sred[2] + sred[3] + 1e-4f;
    __syncthreads();
    const float scale = 1.0f / stot;

    unsigned short* wsu = (unsigned short*)(ws + PFLOATS);
    unsigned int* dstH = (unsigned int*)(wsu + (which ? FYH_U : FXH_U) + ((size_t)b * NOUT + n) * 512);
    unsigned int* dstL = (unsigned int*)(wsu + (which ? FYL_U : FXL_U) + ((size_t)b * NOUT + n) * 512);

    float v0 = f0 * scale;
    float v1 = f1 * scale;
    unsigned short h0 = f2bf(v0);
    unsigned short h1 = f2bf(v1);
    unsigned short l0 = f2bf(v0 - bf2f(h0));
    unsigned short l1 = f2bf(v1 - bf2f(h1));
    dstH[t] = (unsigned int)h0 | ((unsigned int)h1 << 16);
    dstL[t] = (unsigned int)l0 | ((unsigned int)l1 << 16);
}

// ---------------- kernel 3: MFMA glimpse ----------------
// out[b,c] += gamma * Fy_chunk @ (X_chunk @ Fx^T), split-bf16 (hi+lo) MFMA.
// grid (8 hc, 96 bc), 256 threads = 4 waves.
// GEMM1: A (X rows) loaded DIRECT global->fragment (row = 16*wv + l15, k = quad*8)
//        — no X LDS staging at all. Fx chunks double-buffered in LDS:
//        one barrier per tile; next-tile filter loads issue before the MFMAs.
#define KC 64
#define PITCH 72            // ushorts per LDS row (16B-aligned rows, low-conflict)
#define TSZ (64 * PITCH)    // 4608 ushorts per array

__global__ __launch_bounds__(256) void k_glimpse(const float* __restrict__ X,
                                                 const float* __restrict__ ws,
                                                 float* __restrict__ out) {
    const int hc = blockIdx.x;   // 0..7
    const int bc = blockIdx.y;   // 0..95
    const int b = bc / 3;
    const int t = threadIdx.x;
    const int lane = t & 63;
    const int wv = t >> 6;       // 0..3
    const int l15 = lane & 15;
    const int quad = lane >> 4;  // 0..3
    const int hbase = hc * 64;

    __shared__ __align__(16) unsigned short lds[4 * TSZ];   // 36864 B
    unsigned short* Xh = lds;             // odd-tile Fx hi -> later Gt hi
    unsigned short* Xl = lds + TSZ;       // odd-tile Fx lo -> later Gt lo
    unsigned short* Fh = lds + 2 * TSZ;   // even-tile Fx hi -> later Fy hi
    unsigned short* Fl = lds + 3 * TSZ;   // even-tile Fx lo -> later Fy lo

    const float* Xp = X + (size_t)bc * (H_ * W_) + (size_t)hbase * W_;
    const unsigned short* wsu = (const unsigned short*)(ws + PFLOATS);
    const unsigned short* FxHp = wsu + FXH_U + (size_t)b * NOUT * 512;
    const unsigned short* FxLp = wsu + FXL_U + (size_t)b * NOUT * 512;
    const unsigned short* FyHp = wsu + FYH_U + (size_t)b * NOUT * 512;
    const unsigned short* FyLp = wsu + FYL_U + (size_t)b * NOUT * 512;

    // per-lane X row pointer for direct A-fragment loads
    const float* xlane = Xp + (size_t)(16 * wv + l15) * W_ + quad * 8;

    // staging index mapping (Fx/Fy chunks): thread covers 2 rows x 16B
    const int srow0 = t >> 3;              // 0..31
    const int sc8 = (t & 7) * 8;           // 0,8,..56

    // ---- prologue: stage Fx tile 0 into Fh/Fl ----
    {
        uint4 h0 = *(const uint4*)(FxHp + (size_t)srow0 * 512 + sc8);
        uint4 l0 = *(const uint4*)(FxLp + (size_t)srow0 * 512 + sc8);
        uint4 h1 = *(const uint4*)(FxHp + (size_t)(srow0 + 32) * 512 + sc8);
        uint4 l1 = *(const uint4*)(FxLp + (size_t)(srow0 + 32) * 512 + sc8);
        *(uint4*)&Fh[srow0 * PITCH + sc8] = h0;
        *(uint4*)&Fl[srow0 * PITCH + sc8] = l0;
        *(uint4*)&Fh[(srow0 + 32) * PITCH + sc8] = h1;
        *(uint4*)&Fl[(srow0 + 32) * PITCH + sc8] = l1;
    }
    __syncthreads();

    f32x4 acc[4] = {};   // G: wave rows [16wv,+16), 4 m-tiles

    #pragma unroll
    for (int wt = 0; wt < 8; wt++) {
        unsigned short* curH = (wt & 1) ? Xh : Fh;
        unsigned short* curL = (wt & 1) ? Xl : Fl;
        unsigned short* nxtH = (wt & 1) ? Fh : Xh;
        unsigned short* nxtL = (wt & 1) ? Fl : Xl;

        // issue next-tile filter loads (latency hides under the MFMAs below)
        uint4 nh0, nl0, nh1, nl1;
        if (wt < 7) {
            const int wb = (wt + 1) * KC;
            nh0 = *(const uint4*)(FxHp + (size_t)srow0 * 512 + wb + sc8);
            nl0 = *(const uint4*)(FxLp + (size_t)srow0 * 512 + wb + sc8);
            nh1 = *(const uint4*)(FxHp + (size_t)(srow0 + 32) * 512 + wb + sc8);
            nl1 = *(const uint4*)(FxLp + (size_t)(srow0 + 32) * 512 + wb + sc8);
        }

        // ---- GEMM1 MFMAs on current tile; X loaded direct to fragments ----
        #pragma unroll
        for (int ks = 0; ks < 2; ks++) {
            const float* xp = xlane + wt * KC + ks * 32;
            float4 x0 = *(const float4*)(xp);
            float4 x1 = *(const float4*)(xp + 4);
            BF8U ah, al;
            ah.u.x = cvt_pk_bf16(x0.x, x0.y);
            ah.u.y = cvt_pk_bf16(x0.z, x0.w);
            ah.u.z = cvt_pk_bf16(x1.x, x1.y);
            ah.u.w = cvt_pk_bf16(x1.z, x1.w);
            al.u.x = cvt_pk_bf16(x0.x - __uint_as_float(ah.u.x << 16),
                                 x0.y - __uint_as_float(ah.u.x & 0xffff0000u));
            al.u.y = cvt_pk_bf16(x0.z - __uint_as_float(ah.u.y << 16),
                                 x0.w - __uint_as_float(ah.u.y & 0xffff0000u));
            al.u.z = cvt_pk_bf16(x1.x - __uint_as_float(ah.u.z << 16),
                                 x1.y - __uint_as_float(ah.u.z & 0xffff0000u));
            al.u.w = cvt_pk_bf16(x1.z - __uint_as_float(ah.u.w << 16),
                                 x1.w - __uint_as_float(ah.u.w & 0xffff0000u));

            const int ko = ks * 32 + quad * 8;
            #pragma unroll
            for (int mt = 0; mt < 4; mt++) {
                bf16x8 bh = *(const bf16x8*)&curH[(16 * mt + l15) * PITCH + ko];
                bf16x8 bl2 = *(const bf16x8*)&curL[(16 * mt + l15) * PITCH + ko];
                acc[mt] = __builtin_amdgcn_mfma_f32_16x16x32_bf16(ah.v, bh, acc[mt], 0, 0, 0);
                acc[mt] = __builtin_amdgcn_mfma_f32_16x16x32_bf16(al.v, bh, acc[mt], 0, 0, 0);
                acc[mt] = __builtin_amdgcn_mfma_f32_16x16x32_bf16(ah.v, bl2, acc[mt], 0, 0, 0);
            }
        }

        // write prefetched next tile into the other buffer
        if (wt < 7) {
            *(uint4*)&nxtH[srow0 * PITCH + sc8] = nh0;
            *(uint4*)&nxtL[srow0 * PITCH + sc8] = nl0;
            *(uint4*)&nxtH[(srow0 + 32) * PITCH + sc8] = nh1;
            *(uint4*)&nxtL[(srow0 + 32) * PITCH + sc8] = nl1;
        }
        __syncthreads();
    }

    // write G transposed as hi/lo into Xh/Xl region: Gt[m][h]
    #pragma unroll
    for (int mt = 0; mt < 4; mt++) {
        float g0 = acc[mt][0], g1 = acc[mt][1], g2 = acc[mt][2], g3 = acc[mt][3];
        unsigned int h01 = cvt_pk_bf16(g0, g1);
        unsigned int h23 = cvt_pk_bf16(g2, g3);
        float r0 = __uint_as_float(h01 << 16);
        float r1 = __uint_as_float(h01 & 0xffff0000u);
        float r2 = __uint_as_float(h23 << 16);
        float r3 = __uint_as_float(h23 & 0xffff0000u);
        unsigned int l01 = cvt_pk_bf16(g0 - r0, g1 - r1);
        unsigned int l23 = cvt_pk_bf16(g2 - r2, g3 - r3);
        int m = 16 * mt + l15;
        int h = 16 * wv + quad * 4;      // rows quad*4+r, r contiguous
        int o = m * PITCH + h;
        *(uint2*)&Xh[o] = make_uint2(h01, h23);
        *(uint2*)&Xl[o] = make_uint2(l01, l23);
    }

    // stage Fy chunk hi/lo into Fh/Fl
    {
        uint4 h0 = *(const uint4*)(FyHp + (size_t)srow0 * 512 + hbase + sc8);
        uint4 l0 = *(const uint4*)(FyLp + (size_t)srow0 * 512 + hbase + sc8);
        uint4 h1 = *(const uint4*)(FyHp + (size_t)(srow0 + 32) * 512 + hbase + sc8);
        uint4 l1 = *(const uint4*)(FyLp + (size_t)(srow0 + 32) * 512 + hbase + sc8);
        *(uint4*)&Fh[srow0 * PITCH + sc8] = h0;
        *(uint4*)&Fl[srow0 * PITCH + sc8] = l0;
        *(uint4*)&Fh[(srow0 + 32) * PITCH + sc8] = h1;
        *(uint4*)&Fl[(srow0 + 32) * PITCH + sc8] = l1;
    }
    __syncthreads();

    // GEMM2: P[n][m] = sum_h Fy[n][h] * G[h][m]
    f32x4 p[4] = {};
    #pragma unroll
    for (int ks = 0; ks < 2; ks++) {
        const int ko = ks * 32 + quad * 8;
        bf16x8 yh = *(const bf16x8*)&Fh[(16 * wv + l15) * PITCH + ko];
        bf16x8 yl = *(const bf16x8*)&Fl[(16 * wv + l15) * PITCH + ko];
        #pragma unroll
        for (int mt = 0; mt < 4; mt++) {
            bf16x8 gh = *(const bf16x8*)&Xh[(16 * mt + l15) * PITCH + ko];
            bf16x8 gl = *(const bf16x8*)&Xl[(16 * mt + l15) * PITCH + ko];
            p[mt] = __builtin_amdgcn_mfma_f32_16x16x32_bf16(yh, gh, p[mt], 0, 0, 0);
            p[mt] = __builtin_amdgcn_mfma_f32_16x16x32_bf16(yl, gh, p[mt], 0, 0, 0);
            p[mt] = __builtin_amdgcn_mfma_f32_16x16x32_bf16(yh, gl, p[mt], 0, 0, 0);
        }
    }

    const float gamma = ws[GAMMA_OFF + b];
    float* outp = out + (size_t)bc * (NOUT * NOUT);
    #pragma unroll
    for (int mt = 0; mt < 4; mt++)
        #pragma unroll
        for (int r = 0; r < 4; r++) {
            int n = 16 * wv + quad * 4 + r;
            int m = 16 * mt + l15;
            atomicAdd(&outp[n * NOUT + m], gamma * p[mt][r]);
        }
}

extern "C" void kernel_launch(void* const* d_in, const int* in_sizes, int n_in,
                              void* d_out, int out_size, void* d_ws, size_t ws_size,
                              hipStream_t stream) {
    const float* X  = (const float*)d_in[0];
    const float* Wl = (const float*)d_in[1];
    const float* bl = (const float*)d_in[2];
    float* out = (float*)d_out;
    float* ws  = (float*)d_ws;

    k_locnet<<<dim3(CHUNKS, BGROUPS), 256, 0, stream>>>(X, Wl, ws);
    k_filters<<<dim3(NOUT, B_, 2), 256, 0, stream>>>(bl, ws, out);
    k_glimpse<<<dim3(8, B_ * C_), 256, 0, stream>>>(X, ws, out);
}